// Round 7
// baseline (172.381 us; speedup 1.0000x reference)
//
#include <hip/hip_runtime.h>
#include <math.h>

#define B_ 8
#define L_ 4096
#define DM 128
#define DI 256
#define DSN 16
#define RK 8
#define M_ (B_*L_)      // 32768 positions
#define NC 128          // number of scan chunks
#define CH 32           // chunk length (NC*CH == L_)
#define CH2 64          // fused phase3 tile: 2 chunks

typedef __attribute__((ext_vector_type(8))) short bfrag;   // 8 bf16 (4 VGPRs)
typedef __attribute__((ext_vector_type(4))) float ffrag;   // 4 fp32 acc
typedef __attribute__((ext_vector_type(2))) float f32x2;   // packed-math pair

// fast silu: v_exp + v_rcp (hardware approx, ~22-bit — far above bf16 needs)
__device__ __forceinline__ float silu_f(float x) {
  return x * __builtin_amdgcn_rcpf(1.f + __expf(-x));
}
// fast softplus: v_exp + v_log instead of libm log1pf
__device__ __forceinline__ float softplus_f(float x) {
  return (x > 20.f) ? x : __logf(1.f + __expf(x));
}

__device__ __forceinline__ unsigned short f2bf(float f) {
  unsigned int u = __builtin_bit_cast(unsigned int, f);
  unsigned int r = (u + 0x7FFFu + ((u >> 16) & 1u)) >> 16;   // RNE
  return (unsigned short)r;
}
__device__ __forceinline__ unsigned int f2bf2(float lo, float hi) {
  return (unsigned int)f2bf(lo) | ((unsigned int)f2bf(hi) << 16);
}
__device__ __forceinline__ float bf2f(unsigned int us) {
  return __builtin_bit_cast(float, us << 16);
}

// ---------------------------------------------------------------------------
// One-shot weight prep: f32 -> bf16 (same RNE as before -> bit-identical).
// Removes the per-block re-conversion (65K values/block in xproj, 49K in
// scan3) and halves weight-staging bytes. 31232 float4s total.
// ---------------------------------------------------------------------------
__global__ __launch_bounds__(256)
void prep_weights(const float* __restrict__ w_in, const float* __restrict__ xw,
                  const float* __restrict__ ow, const float* __restrict__ fcw,
                  unsigned short* __restrict__ w_in_b, unsigned short* __restrict__ xw_b,
                  unsigned short* __restrict__ ow_b, unsigned short* __restrict__ fcw_b) {
  const int i = blockIdx.x * 256 + threadIdx.x;
  const float* src; unsigned short* dst; int j;
  if (i < 16384)      { src = w_in; dst = w_in_b; j = i; }           // 512x128
  else if (i < 18944) { src = xw;   dst = xw_b;   j = i - 16384; }   // 40x256
  else if (i < 27136) { src = ow;   dst = ow_b;   j = i - 18944; }   // 128x256
  else if (i < 31232) { src = fcw;  dst = fcw_b;  j = i - 27136; }   // 128x128
  else return;
  float4 v = *(const float4*)&src[j << 2];
  uint2 p = {f2bf2(v.x, v.y), f2bf2(v.z, v.w)};
  *(uint2*)&dst[j << 2] = p;
}

// ---------------------------------------------------------------------------
// MEGA-FUSED front end: in_proj GEMM (x half -> LDS, z half -> silu -> zsb)
// + conv(4)+SiLU + x_proj MFMA + dt_proj + INLINE scan phase 1.
// Weights arrive pre-converted bf16 (prep_weights) -> staging is pure
// uint4 copy, no RNE math.
// LDS pool 74.5 KB with phase overlays (unchanged from round 4).
// ---------------------------------------------------------------------------
__global__ __launch_bounds__(512, 4)
void xproj_dtproj(const float* __restrict__ s, const unsigned short* __restrict__ w_in_b,
                  const unsigned short* __restrict__ xw_b,
                  const float* __restrict__ dtw, const float* __restrict__ dtpb,
                  const float* __restrict__ cw, const float* __restrict__ cb,
                  const float* __restrict__ alog,
                  float* __restrict__ Bb, float* __restrict__ Cb,
                  unsigned int* __restrict__ udt,
                  unsigned short* __restrict__ zsb,
                  unsigned short* __restrict__ cP, unsigned short* __restrict__ cHe) {
  __shared__ __align__(16) char pool[74544];
  unsigned short* As = (unsigned short*)pool;              // 80*136*2 = 21760
  unsigned short* Ws = (unsigned short*)(pool + 21760);    // 64*136*2 = 17408
  unsigned short* ua = (unsigned short*)pool;              // 64*264*2 = 33792 (overlay As+Ws)
  unsigned short* hx = (unsigned short*)(pool + 39168);    // 67*264*2 = 35376
  unsigned short* wb = (unsigned short*)(pool + 39168);    // 48*264*2 = 25344 (overlay hx)
  float* dtr_s = (float*)(pool + 64512);                   // 64*12*4  = 3072
  float* Bs_l  = (float*)(pool + 67584);                   // 64*16*4  = 4096
  const int t = threadIdx.x;
  const int p0 = blockIdx.x << 6;
  const int w = t >> 6, l = t & 63, q = l >> 4, col = l & 15;

  // ---- P1: stage A (64 main rows + 16 halo rows of s, f32 -> bf16) ----
  for (int i = t; i < 80 * 32; i += 512) {
    int row = i >> 5, c4 = i & 31;
    int pos = (row < 64) ? (p0 + row) : (p0 - 16 + (row - 64));
    if (pos < 0) pos = 0;                       // block 0 halo: clamped, masked later
    float4 av = *(const float4*)&s[pos * 128 + (c4 << 2)];
    uint2 ap = {f2bf2(av.x, av.y), f2bf2(av.z, av.w)};
    *(uint2*)&As[row * 136 + (c4 << 2)] = ap;
  }
  // W pass 0 into Ws (bf16 uint4 copy; 1024 uint4 per pass, 2/thread)
  uint4 wrb[2];
#pragma unroll
  for (int k = 0; k < 2; ++k) {
    int i = t + (k << 9);
    int row = i >> 4, c8 = (i & 15) << 3;
    wrb[k] = *(const uint4*)&w_in_b[row * 128 + c8];
  }
#pragma unroll
  for (int k = 0; k < 2; ++k) {
    int i = t + (k << 9);
    int row = i >> 4, c8 = (i & 15) << 3;
    *(uint4*)&Ws[row * 136 + c8] = wrb[k];
  }
  __syncthreads();
  // ---- in_proj: 8 passes of 64 W rows (0-3: x half, 4-7: z half) ----
  for (int jt = 0; jt < 8; ++jt) {
    if (jt < 7) {
#pragma unroll
      for (int k = 0; k < 2; ++k) {
        int i = t + (k << 9);
        int row = i >> 4, c8 = (i & 15) << 3;
        wrb[k] = *(const uint4*)&w_in_b[(((jt + 1) << 6) + row) * 128 + c8];
      }
    }
    const int T = (jt < 4) ? 20 : 16;           // x passes include halo m-tile 4
    for (int tile = w; tile < T; tile += 8) {
      const int mt = tile >> 2, nt = tile & 3;
      ffrag acc = {0.f, 0.f, 0.f, 0.f};
#pragma unroll
      for (int s8 = 0; s8 < 4; ++s8) {
        int k0 = s8 * 32 + q * 8;
        bfrag af = *(const bfrag*)&As[((mt << 4) + col) * 136 + k0];
        bfrag bf_ = *(const bfrag*)&Ws[((nt << 4) + col) * 136 + k0];
        acc = __builtin_amdgcn_mfma_f32_16x16x32_bf16(af, bf_, acc, 0, 0, 0);
      }
      if (jt < 4) {
        const int ch = (jt << 6) + (nt << 4) + col;
#pragma unroll
        for (int i = 0; i < 4; ++i) {
          int rt = (q << 2) + i;
          if (mt < 4) {
            hx[(3 + (mt << 4) + rt) * 264 + ch] = f2bf(acc[i]);
          } else {
            int hr = rt - 13;                   // halo rows: positions p0-3..p0-1
            if (hr >= 0) hx[hr * 264 + ch] = f2bf(acc[i]);
          }
        }
      } else {
        const int ch = ((jt - 4) << 6) + (nt << 4) + col;
#pragma unroll
        for (int i = 0; i < 4; ++i) {
          int m = p0 + (mt << 4) + (q << 2) + i;
          zsb[m * 256 + ch] = f2bf(silu_f(acc[i]));
        }
      }
    }
    __syncthreads();
    if (jt < 7) {
#pragma unroll
      for (int k = 0; k < 2; ++k) {
        int i = t + (k << 9);
        int row = i >> 4, c8 = (i & 15) << 3;
        *(uint4*)&Ws[row * 136 + c8] = wrb[k];
      }
      __syncthreads();
    }
  }
  // ---- P2: conv(4)+SiLU from hx (LDS) -> ua (overlays As/Ws) ----
  {
    const int k = t & 255, half = t >> 8;
    const int pstart = half << 5;
    const int base = p0 + pstart;
    const int lb = base & (L_ - 1);
    const float w0 = cw[k*4], w1 = cw[k*4+1], w2 = cw[k*4+2], w3 = cw[k*4+3];
    const float bias = cb[k];
    float x0 = (lb >= 3) ? bf2f((unsigned int)hx[(pstart + 0) * 264 + k]) : 0.f;
    float x1 = (lb >= 2) ? bf2f((unsigned int)hx[(pstart + 1) * 264 + k]) : 0.f;
    float x2 = (lb >= 1) ? bf2f((unsigned int)hx[(pstart + 2) * 264 + k]) : 0.f;
#pragma unroll 8
    for (int it = 0; it < 32; ++it) {
      float x3 = bf2f((unsigned int)hx[(pstart + 3 + it) * 264 + k]);
      float u = silu_f(fmaf(w0, x0, fmaf(w1, x1, fmaf(w2, x2, fmaf(w3, x3, bias)))));
      ua[(pstart + it) * 264 + k] = f2bf(u);
      x0 = x1; x1 = x2; x2 = x3;
    }
  }
  __syncthreads();
  // ---- P3: stage xw (bf16 copy; wb overlays hx) ----
  for (int i = t; i < 40 * 32; i += 512) {
    int row = i >> 5, c8 = (i & 31) << 3;
    *(uint4*)&wb[row * 264 + c8] = *(const uint4*)&xw_b[row * 256 + c8];
  }
  for (int i = t; i < 8 * 264; i += 512) wb[40 * 264 + i] = 0;
  __syncthreads();
  // x_proj MFMA (12 tiles over 8 waves)
  for (int tile = w; tile < 12; tile += 8) {
    const int mt = tile & 3, nt = tile >> 2;
    ffrag acc = {0.f, 0.f, 0.f, 0.f};
#pragma unroll
    for (int s8 = 0; s8 < 8; ++s8) {
      int k0 = s8 * 32 + q * 8;
      bfrag af = *(const bfrag*)&ua[((mt << 4) + col) * 264 + k0];
      bfrag bf_ = *(const bfrag*)&wb[((nt << 4) + col) * 264 + k0];
      acc = __builtin_amdgcn_mfma_f32_16x16x32_bf16(af, bf_, acc, 0, 0, 0);
    }
#pragma unroll
    for (int i = 0; i < 4; ++i) {
      int ml = (mt << 4) + (q << 2) + i;
      int m = p0 + ml;
      if (nt == 0) {
        if (col < 8) dtr_s[ml * 12 + col] = acc[i];
        else {
          Bb[m * 16 + (col - 8)] = acc[i];
          Bs_l[ml * 16 + (col - 8)] = acc[i];
        }
      } else if (nt == 1) {
        if (col < 8) {
          Bb[m * 16 + 8 + col] = acc[i];
          Bs_l[ml * 16 + 8 + col] = acc[i];
        } else {
          Cb[m * 16 + (col - 8)] = acc[i];
        }
      } else {
        if (col < 8) Cb[m * 16 + 8 + col] = acc[i];
      }
    }
  }
  __syncthreads();
  // ---- dt_proj + softplus + inline scan phase 1 ----
  {
    const int d = t & 255, half = t >> 8;
    const int pstart = half << 5;
    const int gpos = p0 + pstart;             // this thread's chunk start (global)
    const int bb = gpos >> 12;                // batch
    const int cc = (gpos & (L_ - 1)) >> 5;    // chunk within batch
    const int bc = bb * NC + cc;
    float w8[8];
    *(float4*)&w8[0] = *(const float4*)&dtw[d * 8];
    *(float4*)&w8[4] = *(const float4*)&dtw[d * 8 + 4];
    const float bias = dtpb[d];
    float a[16];
    bool okl = true;
#pragma unroll
    for (int j = 0; j < 16; ++j) {
      a[j] = -__expf(alog[d * 16 + j]);
      float tgt = (float)(j + 1);
      okl = okl && (fabsf(a[j] + tgt) <= 1e-3f * tgt);
    }
    const bool fast = (bool)__all((int)okl);
    f32x2 h2[8] = {{0.f,0.f},{0.f,0.f},{0.f,0.f},{0.f,0.f},
                   {0.f,0.f},{0.f,0.f},{0.f,0.f},{0.f,0.f}};
    float sdt = 0.f;
#pragma unroll 2
    for (int pp = pstart; pp < pstart + 32; ++pp) {
      float r0[8];
      *(float4*)&r0[0] = *(const float4*)&dtr_s[pp * 12];
      *(float4*)&r0[4] = *(const float4*)&dtr_s[pp * 12 + 4];
      float a2 = bias;
#pragma unroll
      for (int r2 = 0; r2 < 8; ++r2) a2 = fmaf(r0[r2], w8[r2], a2);
      float sp = softplus_f(a2);
      unsigned int uq = (unsigned int)ua[pp * 264 + d];
      unsigned short spb = f2bf(sp);
      udt[(p0 + pp) * 256 + d] = uq | ((unsigned int)spb << 16);
      float dtv = bf2f((unsigned int)spb);
      float uv  = bf2f(uq);
      float du = dtv * uv;
      sdt += dtv;
      const float* brow = &Bs_l[pp * 16];
      float4 b0 = *(const float4*)&brow[0];
      float4 b1 = *(const float4*)&brow[4];
      float4 b2 = *(const float4*)&brow[8];
      float4 b3 = *(const float4*)&brow[12];
      f32x2 B2[8] = {{b0.x,b0.y},{b0.z,b0.w},{b1.x,b1.y},{b1.z,b1.w},
                     {b2.x,b2.y},{b2.z,b2.w},{b3.x,b3.y},{b3.z,b3.w}};
      f32x2 du2 = {du, du};
      if (fast) {
        float e1 = __expf(-dtv);
        float e2 = e1 * e1;
        f32x2 dA = {e1, e2};
        f32x2 e22 = {e2, e2};
#pragma unroll
        for (int jj = 0; jj < 8; ++jj) {
          h2[jj] = dA * h2[jj] + du2 * B2[jj];
          dA = dA * e22;
        }
      } else {
#pragma unroll
        for (int j = 0; j < 16; ++j) {
          float dA = __expf(dtv * a[j]);
          h2[j >> 1][j & 1] = fmaf(dA, h2[j >> 1][j & 1], du * B2[j >> 1][j & 1]);
        }
      }
    }
#pragma unroll
    for (int j = 0; j < 16; ++j) {
      int o = (bc * 16 + j) * 256 + d;
      cP[o]  = f2bf(__expf(a[j] * sdt));
      cHe[o] = f2bf(h2[j >> 1][j & 1]);
    }
  }
}

// ---------------------------------------------------------------------------
// Hierarchical combine (NC=128, bf16): 512 thr = 64 sd x 8 segments of 16.
// ---------------------------------------------------------------------------
__global__ __launch_bounds__(512)
void scan_combine(unsigned short* __restrict__ cP, const unsigned short* __restrict__ cHe) {
  __shared__ float segP[64 * 9], segH[64 * 9], segS[64 * 9];
  const int t = threadIdx.x;
  const int sdl = t & 63, seg = t >> 6;
  const int blk = blockIdx.x;
  const int b = blk >> 6, grp = blk & 63;
  const int sd = (grp << 6) + sdl;
  const int base = b * NC * 4096 + sd;
  float Pacc = 1.f, Hacc = 0.f;
#pragma unroll
  for (int i = 0; i < 16; ++i) {
    int idx = base + (seg * 16 + i) * 4096;
    float p = bf2f((unsigned int)cP[idx]);
    float he = bf2f((unsigned int)cHe[idx]);
    Hacc = fmaf(p, Hacc, he);
    Pacc *= p;
  }
  segP[sdl * 9 + seg] = Pacc;
  segH[sdl * 9 + seg] = Hacc;
  __syncthreads();
  if (t < 64) {
    float hs = 0.f;
#pragma unroll
    for (int s2 = 0; s2 < 8; ++s2) {
      segS[t * 9 + s2] = hs;
      hs = fmaf(segP[t * 9 + s2], hs, segH[t * 9 + s2]);
    }
  }
  __syncthreads();
  float hs = segS[sdl * 9 + seg];
#pragma unroll
  for (int i = 0; i < 16; ++i) {
    int idx = base + (seg * 16 + i) * 4096;
    float p = bf2f((unsigned int)cP[idx]);
    float he = bf2f((unsigned int)cHe[idx]);
    cP[idx] = f2bf(hs);
    hs = fmaf(p, hs, he);
  }
}

// ---------------------------------------------------------------------------
// FUSED scan phase 3 + out_proj + LayerNorm + fc + ReLU.
// Block = 64 positions = 2 chunks scanned IN PARALLEL. Weights arrive bf16
// (prep_weights) -> staging is pure uint4 copy.
// LDS: Bs 4K + Cs 4K + ya 33.8K + smB 34.8K = 76.6 KB -> 2 blocks/CU.
// ---------------------------------------------------------------------------
__global__ __launch_bounds__(512, 4)
void scan3_out_ln_fc(const unsigned int* __restrict__ udt,
                     const float* __restrict__ Bb, const float* __restrict__ Cb,
                     const float* __restrict__ alog, const unsigned short* __restrict__ hst,
                     const float* __restrict__ dsk,
                     const unsigned short* __restrict__ zsb,
                     const unsigned short* __restrict__ ow_b,
                     const float* __restrict__ gamma, const float* __restrict__ beta,
                     const unsigned short* __restrict__ fcw_b, float* __restrict__ out) {
  __shared__ float Bs[CH2 * 16];             // 4 KB
  __shared__ float Cs[CH2 * 16];             // 4 KB
  __shared__ unsigned short smA[64 * 264];   // ya (stride 264); later hnb (stride 136)
  __shared__ unsigned short smB[128 * 136];  // ow halves (stride 264); later fcw (136)
  const int bc = blockIdx.x;
  const int b = bc >> 6, cc = bc & 63;
  const int t = threadIdx.x;
  const int l = t & 63, w = t >> 6;
  const int chh = t >> 8;                     // which of the 2 parallel chunks
  const int d = t & 255;                      // channel
  const int base = b * L_ + (cc << 1) * CH;   // 64-position tile start
  const int cbase = base + chh * CH;          // this chunk's start
  const int hc = b * NC + (cc << 1) + chh;    // h_start chunk index
  // stage B (threads 0-255) and C (threads 256-511): 64x16 floats each
  if (t < CH2 * 4)           ((float4*)Bs)[t]            = *(const float4*)&Bb[base * 16 + (t << 2)];
  else if (t < CH2 * 8)      ((float4*)Cs)[t - CH2 * 4]  = *(const float4*)&Cb[base * 16 + ((t - CH2 * 4) << 2)];
  // fast-path check: a_s == -(s+1) for all 16 states of this channel
  float a[16];
  bool okl = true;
#pragma unroll
  for (int j = 0; j < 16; ++j) {
    a[j] = -__expf(alog[d * 16 + j]);
    float tgt = (float)(j + 1);
    okl = okl && (fabsf(a[j] + tgt) <= 1e-3f * tgt);
  }
  const bool fast = (bool)__all((int)okl);
  const float dskv = dsk[d];
  f32x2 h2[8];
#pragma unroll
  for (int jj = 0; jj < 8; ++jj) {
    h2[jj][0] = bf2f((unsigned int)hst[(hc * 16 + (jj << 1)) * 256 + d]);
    h2[jj][1] = bf2f((unsigned int)hst[(hc * 16 + (jj << 1) + 1) * 256 + d]);
  }
  unsigned int wv0 = udt[cbase * 256 + d];
  unsigned int wv1 = udt[(cbase + 1) * 256 + d];
  unsigned short zv0 = zsb[cbase * 256 + d];
  unsigned short zv1 = zsb[(cbase + 1) * 256 + d];
  __syncthreads();
#pragma unroll 2
  for (int ll = 0; ll < CH; ++ll) {
    const int l2 = (ll + 2 < CH) ? ll + 2 : CH - 1;
    unsigned int wv2 = udt[(cbase + l2) * 256 + d];
    unsigned short zv2 = zsb[(cbase + l2) * 256 + d];
    const float* brow = &Bs[(chh * CH + ll) * 16];
    const float* crow = &Cs[(chh * CH + ll) * 16];
    float4 b0 = *(const float4*)&brow[0];
    float4 b1 = *(const float4*)&brow[4];
    float4 b2 = *(const float4*)&brow[8];
    float4 b3 = *(const float4*)&brow[12];
    float4 c0 = *(const float4*)&crow[0];
    float4 c1 = *(const float4*)&crow[4];
    float4 c2 = *(const float4*)&crow[8];
    float4 c3 = *(const float4*)&crow[12];
    float uv  = bf2f(wv0 & 0xFFFFu);
    float dtv = bf2f(wv0 >> 16);
    f32x2 B2[8] = {{b0.x,b0.y},{b0.z,b0.w},{b1.x,b1.y},{b1.z,b1.w},
                   {b2.x,b2.y},{b2.z,b2.w},{b3.x,b3.y},{b3.z,b3.w}};
    f32x2 C2[8] = {{c0.x,c0.y},{c0.z,c0.w},{c1.x,c1.y},{c1.z,c1.w},
                   {c2.x,c2.y},{c2.z,c2.w},{c3.x,c3.y},{c3.z,c3.w}};
    float du = dtv * uv;
    f32x2 du2 = {du, du};
    f32x2 y2 = {0.f, 0.f};
    if (fast) {
      float e1 = __expf(-dtv);
      float e2 = e1 * e1;
      f32x2 dA = {e1, e2};        // decay for states 0,1 = e1^1, e1^2
      f32x2 e22 = {e2, e2};
#pragma unroll
      for (int jj = 0; jj < 8; ++jj) {
        h2[jj] = dA * h2[jj] + du2 * B2[jj];
        y2 = y2 + h2[jj] * C2[jj];
        dA = dA * e22;
      }
    } else {
#pragma unroll
      for (int j = 0; j < 16; ++j) {
        float dA = __expf(dtv * a[j]);
        float hh = fmaf(dA, h2[j >> 1][j & 1], du * B2[j >> 1][j & 1]);
        h2[j >> 1][j & 1] = hh;
        y2[j & 1] = fmaf(hh, C2[j >> 1][j & 1], y2[j & 1]);
      }
    }
    float y = y2.x + y2.y;
    float zs = bf2f((unsigned int)zv0);
    smA[(chh * CH + ll) * 264 + d] = f2bf(fmaf(uv, dskv, y) * zs);   // ya, bf16
    wv0 = wv1; wv1 = wv2; zv0 = zv1; zv1 = zv2;
  }
  // ---------------- epilogue: out_proj -> LN -> fc -> ReLU ----------------
  const int q = l >> 4, col = l & 15;
  ffrag acc[2][4];
  for (int nt2 = 0; nt2 < 2; ++nt2) {
    __syncthreads();           // iter0: ya complete; iterN: prior MFMA reads done
    for (int i = t; i < 64 * 32; i += 512) {
      int row = i >> 5, c8 = (i & 31) << 3;
      *(uint4*)&smB[row * 264 + c8] = *(const uint4*)&ow_b[((nt2 << 6) + row) * 256 + c8];
    }
    __syncthreads();
    if (t < 256) {
#pragma unroll
      for (int nt = 0; nt < 4; ++nt) acc[nt2][nt] = (ffrag){0.f, 0.f, 0.f, 0.f};
#pragma unroll
      for (int s8 = 0; s8 < 8; ++s8) {
        int k0 = s8 * 32 + q * 8;
        bfrag af = *(const bfrag*)&smA[((w << 4) + col) * 264 + k0];
#pragma unroll
        for (int nt = 0; nt < 4; ++nt) {
          bfrag bf_ = *(const bfrag*)&smB[((nt << 4) + col) * 264 + k0];
          acc[nt2][nt] = __builtin_amdgcn_mfma_f32_16x16x32_bf16(af, bf_, acc[nt2][nt], 0, 0, 0);
        }
      }
    }
  }
  float mu[4], rs[4];
  if (t < 256) {
#pragma unroll
    for (int i = 0; i < 4; ++i) {
      float s1 = 0.f, s2 = 0.f;
#pragma unroll
      for (int nt2 = 0; nt2 < 2; ++nt2)
#pragma unroll
        for (int nt = 0; nt < 4; ++nt) {
          float v = acc[nt2][nt][i];
          s1 += v; s2 = fmaf(v, v, s2);
        }
      s1 += __shfl_xor(s1, 1); s2 += __shfl_xor(s2, 1);
      s1 += __shfl_xor(s1, 2); s2 += __shfl_xor(s2, 2);
      s1 += __shfl_xor(s1, 4); s2 += __shfl_xor(s2, 4);
      s1 += __shfl_xor(s1, 8); s2 += __shfl_xor(s2, 8);
      mu[i] = s1 * (1.f / DM);
      float var = s2 * (1.f / DM) - mu[i] * mu[i];
      rs[i] = rsqrtf(var + 1e-5f);
    }
  }
  __syncthreads();   // all MFMA LDS reads done before overlaying smA/smB
  if (t < 256) {
#pragma unroll
    for (int nt2 = 0; nt2 < 2; ++nt2)
#pragma unroll
      for (int nt = 0; nt < 4; ++nt) {
        int n = (nt2 << 6) + (nt << 4) + col;
        float g = gamma[n], be = beta[n];
#pragma unroll
        for (int i = 0; i < 4; ++i) {
          int r = (w << 4) + (q << 2) + i;
          smA[r * 136 + n] = f2bf(fmaf((acc[nt2][nt][i] - mu[i]) * rs[i], g, be));
        }
      }
  }
  for (int i = t; i < 128 * 16; i += 512) {
    int row = i >> 4, c8 = (i & 15) << 3;
    *(uint4*)&smB[row * 136 + c8] = *(const uint4*)&fcw_b[row * 128 + c8];
  }
  __syncthreads();
  if (t < 256) {
    ffrag a2[8] = {{0.f,0.f,0.f,0.f},{0.f,0.f,0.f,0.f},{0.f,0.f,0.f,0.f},{0.f,0.f,0.f,0.f},
                   {0.f,0.f,0.f,0.f},{0.f,0.f,0.f,0.f},{0.f,0.f,0.f,0.f},{0.f,0.f,0.f,0.f}};
#pragma unroll
    for (int s8 = 0; s8 < 4; ++s8) {
      int k0 = s8 * 32 + q * 8;
      bfrag af = *(const bfrag*)&smA[((w << 4) + col) * 136 + k0];
#pragma unroll
      for (int nt = 0; nt < 8; ++nt) {
        bfrag bf_ = *(const bfrag*)&smB[((nt << 4) + col) * 136 + k0];
        a2[nt] = __builtin_amdgcn_mfma_f32_16x16x32_bf16(af, bf_, a2[nt], 0, 0, 0);
      }
    }
#pragma unroll
    for (int nt = 0; nt < 8; ++nt)
#pragma unroll
      for (int i = 0; i < 4; ++i) {
        int ml = (w << 4) + (q << 2) + i;
        out[(base + ml) * 128 + (nt << 4) + col] = fmaxf(a2[nt][i], 0.f);
      }
  }
}

extern "C" void kernel_launch(void* const* d_in, const int* in_sizes, int n_in,
                              void* d_out, int out_size, void* d_ws, size_t ws_size,
                              hipStream_t stream) {
  (void)in_sizes; (void)n_in; (void)out_size; (void)ws_size;
  const float* s    = (const float*)d_in[0];
  const float* w_in = (const float*)d_in[1];
  const float* cw   = (const float*)d_in[2];
  const float* cb   = (const float*)d_in[3];
  const float* xw   = (const float*)d_in[4];
  const float* dtw  = (const float*)d_in[5];
  const float* dtpb = (const float*)d_in[6];
  const float* alog = (const float*)d_in[7];
  const float* dsk  = (const float*)d_in[8];
  const float* ow   = (const float*)d_in[9];
  const float* gam  = (const float*)d_in[10];
  const float* bet  = (const float*)d_in[11];
  const float* fcw  = (const float*)d_in[12];
  float* out = (float*)d_out;
  float* ws  = (float*)d_ws;

  // float-unit offsets; all regions disjoint (re-audited r6 — r5 had bf16
  // regions at HALF size; sizes below are (num bf16 values)/2 floats):
  unsigned short* zsb  = (unsigned short*)(ws + 4194304);     // [4194304, 8388608)
  unsigned int*   udt  = (unsigned int*)(ws + 8388608);       // [8388608, 16777216)
  float*          Bb   = ws + 16777216;                       // [16777216, 17301504)
  float*          Cb   = ws + 17301504;                       // [17301504, 17825792)
  unsigned short* cP   = (unsigned short*)(ws + 17825792);    // [17825792, 19922944)
  unsigned short* cHe  = (unsigned short*)(ws + 19922944);    // [19922944, 22020096)
  unsigned short* w_in_b = (unsigned short*)(ws + 22020096);  // 65536 bf16 -> [22020096, 22052864)
  unsigned short* xw_b   = (unsigned short*)(ws + 22052864);  // 10240 bf16 -> [22052864, 22057984)
  unsigned short* ow_b   = (unsigned short*)(ws + 22057984);  // 32768 bf16 -> [22057984, 22074368)
  unsigned short* fcw_b  = (unsigned short*)(ws + 22074368);  // 16384 bf16 -> [22074368, 22082560)

  // 0. one-shot weight f32->bf16 (identical RNE; removes per-block re-convert)
  prep_weights<<<122, 256, 0, stream>>>(w_in, xw, ow, fcw, w_in_b, xw_b, ow_b, fcw_b);
  // 1. MEGA-FUSED: in_proj + conv/silu + x_proj + dt_proj + scan phase 1
  xproj_dtproj<<<512, 512, 0, stream>>>(s, w_in_b, xw_b, dtw, dtpb, cw, cb, alog,
                                        Bb, Cb, udt, zsb, cP, cHe);
  // 2. inter-chunk combine
  scan_combine<<<512, 512, 0, stream>>>(cP, cHe);
  // 3. FUSED scan phase 3 (2 parallel chunks/block) + out_proj + LN + fc + ReLU
  scan3_out_ln_fc<<<B_ * NC / 2, 512, 0, stream>>>(udt, Bb, Cb, alog, cP, dsk, zsb,
                                                   ow_b, gam, bet, fcw_b, out);
}

// Round 8
// 167.144 us; speedup vs baseline: 1.0313x; 1.0313x over previous
//
#include <hip/hip_runtime.h>
#include <math.h>

#define B_ 8
#define L_ 4096
#define DM 128
#define DI 256
#define DSN 16
#define RK 8
#define M_ (B_*L_)      // 32768 positions
#define NC 128          // number of scan chunks
#define CH 32           // chunk length (NC*CH == L_)
#define CH2 64          // fused phase3 tile: 2 chunks

typedef __attribute__((ext_vector_type(8))) short bfrag;   // 8 bf16 (4 VGPRs)
typedef __attribute__((ext_vector_type(4))) float ffrag;   // 4 fp32 acc
typedef __attribute__((ext_vector_type(2))) float f32x2;   // packed-math pair

// fast silu: v_exp + v_rcp (hardware approx, ~22-bit — far above bf16 needs)
__device__ __forceinline__ float silu_f(float x) {
  return x * __builtin_amdgcn_rcpf(1.f + __expf(-x));
}
// fast softplus: v_exp + v_log instead of libm log1pf
__device__ __forceinline__ float softplus_f(float x) {
  return (x > 20.f) ? x : __logf(1.f + __expf(x));
}

__device__ __forceinline__ unsigned short f2bf(float f) {
  unsigned int u = __builtin_bit_cast(unsigned int, f);
  unsigned int r = (u + 0x7FFFu + ((u >> 16) & 1u)) >> 16;   // RNE
  return (unsigned short)r;
}
__device__ __forceinline__ unsigned int f2bf2(float lo, float hi) {
  return (unsigned int)f2bf(lo) | ((unsigned int)f2bf(hi) << 16);
}
__device__ __forceinline__ float bf2f(unsigned int us) {
  return __builtin_bit_cast(float, us << 16);
}

// ---------------------------------------------------------------------------
// One-shot weight prep: f32 -> bf16 (same RNE as before -> bit-identical).
// w_in_b is REQUIRED by xproj's direct-from-global W fragment loads.
// ---------------------------------------------------------------------------
__global__ __launch_bounds__(256)
void prep_weights(const float* __restrict__ w_in, const float* __restrict__ xw,
                  const float* __restrict__ ow, const float* __restrict__ fcw,
                  unsigned short* __restrict__ w_in_b, unsigned short* __restrict__ xw_b,
                  unsigned short* __restrict__ ow_b, unsigned short* __restrict__ fcw_b) {
  const int i = blockIdx.x * 256 + threadIdx.x;
  const float* src; unsigned short* dst; int j;
  if (i < 16384)      { src = w_in; dst = w_in_b; j = i; }           // 512x128
  else if (i < 18944) { src = xw;   dst = xw_b;   j = i - 16384; }   // 40x256
  else if (i < 27136) { src = ow;   dst = ow_b;   j = i - 18944; }   // 128x256
  else if (i < 31232) { src = fcw;  dst = fcw_b;  j = i - 27136; }   // 128x128
  else return;
  float4 v = *(const float4*)&src[j << 2];
  uint2 p = {f2bf2(v.x, v.y), f2bf2(v.z, v.w)};
  *(uint2*)&dst[j << 2] = p;
}

// ---------------------------------------------------------------------------
// MEGA-FUSED front end, round-8 restructure:
//  * in_proj W fragments read DIRECTLY from global (bf16, L2-resident) —
//    removes the Ws LDS double-staging and 14 of its barriers (19 -> 5).
//  * MFMA operands SWAPPED (bit-identical values, transposed lane layout):
//    lane holds 4 consecutive CHANNELS -> packed uint2 writes to hx/zsb and
//    float4 stores in the x_proj epilogue.
// LDS pool 74.5 KB: [As|ua 33.8K][hx|wb 35.4K][dtr_s 3K][Bs_l 4K].
// ---------------------------------------------------------------------------
__global__ __launch_bounds__(512, 4)
void xproj_dtproj(const float* __restrict__ s, const unsigned short* __restrict__ w_in_b,
                  const unsigned short* __restrict__ xw_b,
                  const float* __restrict__ dtw, const float* __restrict__ dtpb,
                  const float* __restrict__ cw, const float* __restrict__ cb,
                  const float* __restrict__ alog,
                  float* __restrict__ Bb, float* __restrict__ Cb,
                  unsigned int* __restrict__ udt,
                  unsigned short* __restrict__ zsb,
                  unsigned short* __restrict__ cP, unsigned short* __restrict__ cHe) {
  __shared__ __align__(16) char pool[76336];
  unsigned short* As = (unsigned short*)pool;              // 80*136*2 = 21760
  unsigned short* ua = (unsigned short*)pool;              // 64*264*2 = 33792 (overlay As)
  unsigned short* hx = (unsigned short*)(pool + 33792);    // 67*264*2 = 35376
  unsigned short* wb = (unsigned short*)(pool + 33792);    // 48*264*2 = 25344 (overlay hx)
  float* dtr_s = (float*)(pool + 69168);                   // 64*12*4  = 3072
  float* Bs_l  = (float*)(pool + 72240);                   // 64*16*4  = 4096
  const int t = threadIdx.x;
  const int p0 = blockIdx.x << 6;
  const int w = t >> 6, l = t & 63, q = l >> 4, col = l & 15;

  // ---- stage A (64 main rows + 16 halo rows of s, f32 -> bf16) ----
  for (int i = t; i < 80 * 32; i += 512) {
    int row = i >> 5, c4 = i & 31;
    int pos = (row < 64) ? (p0 + row) : (p0 - 16 + (row - 64));
    if (pos < 0) pos = 0;                       // block 0 halo: clamped, masked later
    float4 av = *(const float4*)&s[pos * 128 + (c4 << 2)];
    uint2 ap = {f2bf2(av.x, av.y), f2bf2(av.z, av.w)};
    *(uint2*)&As[row * 136 + (c4 << 2)] = ap;
  }
  __syncthreads();
  // ---- in_proj: barrier-free tile stream; W fragments from global ----
  // x half: jt 0..3, 20 tiles (mt 0..4 incl. halo); z half: jt 4..7, 16 tiles.
  for (int jt = 0; jt < 8; ++jt) {
    const int wrow0 = jt << 6;
    const int T = (jt < 4) ? 20 : 16;
    for (int tile = w; tile < T; tile += 8) {
      const int mt = tile >> 2, nt = tile & 3;
      ffrag acc = {0.f, 0.f, 0.f, 0.f};
#pragma unroll
      for (int s8 = 0; s8 < 4; ++s8) {
        int k0 = s8 * 32 + q * 8;
        bfrag af = *(const bfrag*)&As[((mt << 4) + col) * 136 + k0];
        bfrag wf = *(const bfrag*)&w_in_b[(wrow0 + (nt << 4) + col) * 128 + k0];
        // swapped operands: D[n][m] — lane holds n = nt*16+q*4+i at m = mt*16+col
        acc = __builtin_amdgcn_mfma_f32_16x16x32_bf16(wf, af, acc, 0, 0, 0);
      }
      const int chb = (nt << 4) + (q << 2);     // channel quad within this jt's 64
      if (jt < 4) {
        uint2 pk = {f2bf2(acc[0], acc[1]), f2bf2(acc[2], acc[3])};
        const int ch = (jt << 6) + chb;
        if (mt < 4) {
          *(uint2*)&hx[(3 + (mt << 4) + col) * 264 + ch] = pk;
        } else if (col >= 13) {                 // halo rows: positions p0-3..p0-1
          *(uint2*)&hx[(col - 13) * 264 + ch] = pk;
        }
      } else {
        uint2 pk = {f2bf2(silu_f(acc[0]), silu_f(acc[1])),
                    f2bf2(silu_f(acc[2]), silu_f(acc[3]))};
        const int m = p0 + (mt << 4) + col;
        *(uint2*)&zsb[m * 256 + ((jt - 4) << 6) + chb] = pk;
      }
    }
  }
  __syncthreads();   // hx complete; all As reads done (ua may be overwritten)
  // ---- conv(4)+SiLU from hx (LDS) -> ua (overlays As) ----
  {
    const int k = t & 255, half = t >> 8;
    const int pstart = half << 5;
    const int base = p0 + pstart;
    const int lb = base & (L_ - 1);
    const float w0 = cw[k*4], w1 = cw[k*4+1], w2 = cw[k*4+2], w3 = cw[k*4+3];
    const float bias = cb[k];
    float x0 = (lb >= 3) ? bf2f((unsigned int)hx[(pstart + 0) * 264 + k]) : 0.f;
    float x1 = (lb >= 2) ? bf2f((unsigned int)hx[(pstart + 1) * 264 + k]) : 0.f;
    float x2 = (lb >= 1) ? bf2f((unsigned int)hx[(pstart + 2) * 264 + k]) : 0.f;
#pragma unroll 8
    for (int it = 0; it < 32; ++it) {
      float x3 = bf2f((unsigned int)hx[(pstart + 3 + it) * 264 + k]);
      float u = silu_f(fmaf(w0, x0, fmaf(w1, x1, fmaf(w2, x2, fmaf(w3, x3, bias)))));
      ua[(pstart + it) * 264 + k] = f2bf(u);
      x0 = x1; x1 = x2; x2 = x3;
    }
  }
  __syncthreads();   // conv's hx reads done (wb will overwrite hx)
  // ---- stage xw (bf16 copy; wb overlays hx) ----
  for (int i = t; i < 40 * 32; i += 512) {
    int row = i >> 5, c8 = (i & 31) << 3;
    *(uint4*)&wb[row * 264 + c8] = *(const uint4*)&xw_b[row * 256 + c8];
  }
  for (int i = t; i < 8 * 264; i += 512) wb[40 * 264 + i] = 0;
  __syncthreads();
  // ---- x_proj MFMA (12 tiles over 8 waves), swapped -> float4 stores ----
  for (int tile = w; tile < 12; tile += 8) {
    const int mt = tile & 3, nt = tile >> 2;
    ffrag acc = {0.f, 0.f, 0.f, 0.f};
#pragma unroll
    for (int s8 = 0; s8 < 8; ++s8) {
      int k0 = s8 * 32 + q * 8;
      bfrag af = *(const bfrag*)&ua[((mt << 4) + col) * 264 + k0];
      bfrag wf = *(const bfrag*)&wb[((nt << 4) + col) * 264 + k0];
      acc = __builtin_amdgcn_mfma_f32_16x16x32_bf16(wf, af, acc, 0, 0, 0);
    }
    // lane holds n = nt*16+q*4+i at row ml = mt*16+col
    const int ml = (mt << 4) + col;
    const int m = p0 + ml;
    const int n0 = (nt << 4) + (q << 2);
    float4 v = {acc[0], acc[1], acc[2], acc[3]};
    if (n0 < 8) {
      *(float4*)&dtr_s[ml * 12 + n0] = v;
    } else if (n0 < 24) {
      *(float4*)&Bb[m * 16 + (n0 - 8)] = v;
      *(float4*)&Bs_l[ml * 16 + (n0 - 8)] = v;
    } else if (n0 < 40) {
      *(float4*)&Cb[m * 16 + (n0 - 24)] = v;
    }                                           // n0 >= 40: zero rows, drop
  }
  __syncthreads();
  // ---- dt_proj + softplus + inline scan phase 1 ----
  {
    const int d = t & 255, half = t >> 8;
    const int pstart = half << 5;
    const int gpos = p0 + pstart;             // this thread's chunk start (global)
    const int bb = gpos >> 12;                // batch
    const int cc = (gpos & (L_ - 1)) >> 5;    // chunk within batch
    const int bc = bb * NC + cc;
    float w8[8];
    *(float4*)&w8[0] = *(const float4*)&dtw[d * 8];
    *(float4*)&w8[4] = *(const float4*)&dtw[d * 8 + 4];
    const float bias = dtpb[d];
    float a[16];
    bool okl = true;
#pragma unroll
    for (int j = 0; j < 16; ++j) {
      a[j] = -__expf(alog[d * 16 + j]);
      float tgt = (float)(j + 1);
      okl = okl && (fabsf(a[j] + tgt) <= 1e-3f * tgt);
    }
    const bool fast = (bool)__all((int)okl);
    f32x2 h2[8] = {{0.f,0.f},{0.f,0.f},{0.f,0.f},{0.f,0.f},
                   {0.f,0.f},{0.f,0.f},{0.f,0.f},{0.f,0.f}};
    float sdt = 0.f;
#pragma unroll 2
    for (int pp = pstart; pp < pstart + 32; ++pp) {
      float r0[8];
      *(float4*)&r0[0] = *(const float4*)&dtr_s[pp * 12];
      *(float4*)&r0[4] = *(const float4*)&dtr_s[pp * 12 + 4];
      float a2 = bias;
#pragma unroll
      for (int r2 = 0; r2 < 8; ++r2) a2 = fmaf(r0[r2], w8[r2], a2);
      float sp = softplus_f(a2);
      unsigned int uq = (unsigned int)ua[pp * 264 + d];
      unsigned short spb = f2bf(sp);
      udt[(p0 + pp) * 256 + d] = uq | ((unsigned int)spb << 16);
      float dtv = bf2f((unsigned int)spb);
      float uv  = bf2f(uq);
      float du = dtv * uv;
      sdt += dtv;
      const float* brow = &Bs_l[pp * 16];
      float4 b0 = *(const float4*)&brow[0];
      float4 b1 = *(const float4*)&brow[4];
      float4 b2 = *(const float4*)&brow[8];
      float4 b3 = *(const float4*)&brow[12];
      f32x2 B2[8] = {{b0.x,b0.y},{b0.z,b0.w},{b1.x,b1.y},{b1.z,b1.w},
                     {b2.x,b2.y},{b2.z,b2.w},{b3.x,b3.y},{b3.z,b3.w}};
      f32x2 du2 = {du, du};
      if (fast) {
        float e1 = __expf(-dtv);
        float e2 = e1 * e1;
        f32x2 dA = {e1, e2};
        f32x2 e22 = {e2, e2};
#pragma unroll
        for (int jj = 0; jj < 8; ++jj) {
          h2[jj] = dA * h2[jj] + du2 * B2[jj];
          dA = dA * e22;
        }
      } else {
#pragma unroll
        for (int j = 0; j < 16; ++j) {
          float dA = __expf(dtv * a[j]);
          h2[j >> 1][j & 1] = fmaf(dA, h2[j >> 1][j & 1], du * B2[j >> 1][j & 1]);
        }
      }
    }
#pragma unroll
    for (int j = 0; j < 16; ++j) {
      int o = (bc * 16 + j) * 256 + d;
      cP[o]  = f2bf(__expf(a[j] * sdt));
      cHe[o] = f2bf(h2[j >> 1][j & 1]);
    }
  }
}

// ---------------------------------------------------------------------------
// Hierarchical combine (NC=128, bf16): 512 thr = 64 sd x 8 segments of 16.
// ---------------------------------------------------------------------------
__global__ __launch_bounds__(512)
void scan_combine(unsigned short* __restrict__ cP, const unsigned short* __restrict__ cHe) {
  __shared__ float segP[64 * 9], segH[64 * 9], segS[64 * 9];
  const int t = threadIdx.x;
  const int sdl = t & 63, seg = t >> 6;
  const int blk = blockIdx.x;
  const int b = blk >> 6, grp = blk & 63;
  const int sd = (grp << 6) + sdl;
  const int base = b * NC * 4096 + sd;
  float Pacc = 1.f, Hacc = 0.f;
#pragma unroll
  for (int i = 0; i < 16; ++i) {
    int idx = base + (seg * 16 + i) * 4096;
    float p = bf2f((unsigned int)cP[idx]);
    float he = bf2f((unsigned int)cHe[idx]);
    Hacc = fmaf(p, Hacc, he);
    Pacc *= p;
  }
  segP[sdl * 9 + seg] = Pacc;
  segH[sdl * 9 + seg] = Hacc;
  __syncthreads();
  if (t < 64) {
    float hs = 0.f;
#pragma unroll
    for (int s2 = 0; s2 < 8; ++s2) {
      segS[t * 9 + s2] = hs;
      hs = fmaf(segP[t * 9 + s2], hs, segH[t * 9 + s2]);
    }
  }
  __syncthreads();
  float hs = segS[sdl * 9 + seg];
#pragma unroll
  for (int i = 0; i < 16; ++i) {
    int idx = base + (seg * 16 + i) * 4096;
    float p = bf2f((unsigned int)cP[idx]);
    float he = bf2f((unsigned int)cHe[idx]);
    cP[idx] = f2bf(hs);
    hs = fmaf(p, hs, he);
  }
}

// ---------------------------------------------------------------------------
// FUSED scan phase 3 + out_proj + LayerNorm + fc + ReLU (unchanged from r7).
// ---------------------------------------------------------------------------
__global__ __launch_bounds__(512, 4)
void scan3_out_ln_fc(const unsigned int* __restrict__ udt,
                     const float* __restrict__ Bb, const float* __restrict__ Cb,
                     const float* __restrict__ alog, const unsigned short* __restrict__ hst,
                     const float* __restrict__ dsk,
                     const unsigned short* __restrict__ zsb,
                     const unsigned short* __restrict__ ow_b,
                     const float* __restrict__ gamma, const float* __restrict__ beta,
                     const unsigned short* __restrict__ fcw_b, float* __restrict__ out) {
  __shared__ float Bs[CH2 * 16];             // 4 KB
  __shared__ float Cs[CH2 * 16];             // 4 KB
  __shared__ unsigned short smA[64 * 264];   // ya (stride 264); later hnb (stride 136)
  __shared__ unsigned short smB[128 * 136];  // ow halves (stride 264); later fcw (136)
  const int bc = blockIdx.x;
  const int b = bc >> 6, cc = bc & 63;
  const int t = threadIdx.x;
  const int l = t & 63, w = t >> 6;
  const int chh = t >> 8;                     // which of the 2 parallel chunks
  const int d = t & 255;                      // channel
  const int base = b * L_ + (cc << 1) * CH;   // 64-position tile start
  const int cbase = base + chh * CH;          // this chunk's start
  const int hc = b * NC + (cc << 1) + chh;    // h_start chunk index
  if (t < CH2 * 4)           ((float4*)Bs)[t]            = *(const float4*)&Bb[base * 16 + (t << 2)];
  else if (t < CH2 * 8)      ((float4*)Cs)[t - CH2 * 4]  = *(const float4*)&Cb[base * 16 + ((t - CH2 * 4) << 2)];
  float a[16];
  bool okl = true;
#pragma unroll
  for (int j = 0; j < 16; ++j) {
    a[j] = -__expf(alog[d * 16 + j]);
    float tgt = (float)(j + 1);
    okl = okl && (fabsf(a[j] + tgt) <= 1e-3f * tgt);
  }
  const bool fast = (bool)__all((int)okl);
  const float dskv = dsk[d];
  f32x2 h2[8];
#pragma unroll
  for (int jj = 0; jj < 8; ++jj) {
    h2[jj][0] = bf2f((unsigned int)hst[(hc * 16 + (jj << 1)) * 256 + d]);
    h2[jj][1] = bf2f((unsigned int)hst[(hc * 16 + (jj << 1) + 1) * 256 + d]);
  }
  unsigned int wv0 = udt[cbase * 256 + d];
  unsigned int wv1 = udt[(cbase + 1) * 256 + d];
  unsigned short zv0 = zsb[cbase * 256 + d];
  unsigned short zv1 = zsb[(cbase + 1) * 256 + d];
  __syncthreads();
#pragma unroll 2
  for (int ll = 0; ll < CH; ++ll) {
    const int l2 = (ll + 2 < CH) ? ll + 2 : CH - 1;
    unsigned int wv2 = udt[(cbase + l2) * 256 + d];
    unsigned short zv2 = zsb[(cbase + l2) * 256 + d];
    const float* brow = &Bs[(chh * CH + ll) * 16];
    const float* crow = &Cs[(chh * CH + ll) * 16];
    float4 b0 = *(const float4*)&brow[0];
    float4 b1 = *(const float4*)&brow[4];
    float4 b2 = *(const float4*)&brow[8];
    float4 b3 = *(const float4*)&brow[12];
    float4 c0 = *(const float4*)&crow[0];
    float4 c1 = *(const float4*)&crow[4];
    float4 c2 = *(const float4*)&crow[8];
    float4 c3 = *(const float4*)&crow[12];
    float uv  = bf2f(wv0 & 0xFFFFu);
    float dtv = bf2f(wv0 >> 16);
    f32x2 B2[8] = {{b0.x,b0.y},{b0.z,b0.w},{b1.x,b1.y},{b1.z,b1.w},
                   {b2.x,b2.y},{b2.z,b2.w},{b3.x,b3.y},{b3.z,b3.w}};
    f32x2 C2[8] = {{c0.x,c0.y},{c0.z,c0.w},{c1.x,c1.y},{c1.z,c1.w},
                   {c2.x,c2.y},{c2.z,c2.w},{c3.x,c3.y},{c3.z,c3.w}};
    float du = dtv * uv;
    f32x2 du2 = {du, du};
    f32x2 y2 = {0.f, 0.f};
    if (fast) {
      float e1 = __expf(-dtv);
      float e2 = e1 * e1;
      f32x2 dA = {e1, e2};        // decay for states 0,1 = e1^1, e1^2
      f32x2 e22 = {e2, e2};
#pragma unroll
      for (int jj = 0; jj < 8; ++jj) {
        h2[jj] = dA * h2[jj] + du2 * B2[jj];
        y2 = y2 + h2[jj] * C2[jj];
        dA = dA * e22;
      }
    } else {
#pragma unroll
      for (int j = 0; j < 16; ++j) {
        float dA = __expf(dtv * a[j]);
        float hh = fmaf(dA, h2[j >> 1][j & 1], du * B2[j >> 1][j & 1]);
        h2[j >> 1][j & 1] = hh;
        y2[j & 1] = fmaf(hh, C2[j >> 1][j & 1], y2[j & 1]);
      }
    }
    float y = y2.x + y2.y;
    float zs = bf2f((unsigned int)zv0);
    smA[(chh * CH + ll) * 264 + d] = f2bf(fmaf(uv, dskv, y) * zs);   // ya, bf16
    wv0 = wv1; wv1 = wv2; zv0 = zv1; zv1 = zv2;
  }
  // ---------------- epilogue: out_proj -> LN -> fc -> ReLU ----------------
  const int q = l >> 4, col = l & 15;
  ffrag acc[2][4];
  for (int nt2 = 0; nt2 < 2; ++nt2) {
    __syncthreads();           // iter0: ya complete; iterN: prior MFMA reads done
    for (int i = t; i < 64 * 32; i += 512) {
      int row = i >> 5, c8 = (i & 31) << 3;
      *(uint4*)&smB[row * 264 + c8] = *(const uint4*)&ow_b[((nt2 << 6) + row) * 256 + c8];
    }
    __syncthreads();
    if (t < 256) {
#pragma unroll
      for (int nt = 0; nt < 4; ++nt) acc[nt2][nt] = (ffrag){0.f, 0.f, 0.f, 0.f};
#pragma unroll
      for (int s8 = 0; s8 < 8; ++s8) {
        int k0 = s8 * 32 + q * 8;
        bfrag af = *(const bfrag*)&smA[((w << 4) + col) * 264 + k0];
#pragma unroll
        for (int nt = 0; nt < 4; ++nt) {
          bfrag bf_ = *(const bfrag*)&smB[((nt << 4) + col) * 264 + k0];
          acc[nt2][nt] = __builtin_amdgcn_mfma_f32_16x16x32_bf16(af, bf_, acc[nt2][nt], 0, 0, 0);
        }
      }
    }
  }
  float mu[4], rs[4];
  if (t < 256) {
#pragma unroll
    for (int i = 0; i < 4; ++i) {
      float s1 = 0.f, s2 = 0.f;
#pragma unroll
      for (int nt2 = 0; nt2 < 2; ++nt2)
#pragma unroll
        for (int nt = 0; nt < 4; ++nt) {
          float v = acc[nt2][nt][i];
          s1 += v; s2 = fmaf(v, v, s2);
        }
      s1 += __shfl_xor(s1, 1); s2 += __shfl_xor(s2, 1);
      s1 += __shfl_xor(s1, 2); s2 += __shfl_xor(s2, 2);
      s1 += __shfl_xor(s1, 4); s2 += __shfl_xor(s2, 4);
      s1 += __shfl_xor(s1, 8); s2 += __shfl_xor(s2, 8);
      mu[i] = s1 * (1.f / DM);
      float var = s2 * (1.f / DM) - mu[i] * mu[i];
      rs[i] = rsqrtf(var + 1e-5f);
    }
  }
  __syncthreads();   // all MFMA LDS reads done before overlaying smA/smB
  if (t < 256) {
#pragma unroll
    for (int nt2 = 0; nt2 < 2; ++nt2)
#pragma unroll
      for (int nt = 0; nt < 4; ++nt) {
        int n = (nt2 << 6) + (nt << 4) + col;
        float g = gamma[n], be = beta[n];
#pragma unroll
        for (int i = 0; i < 4; ++i) {
          int r = (w << 4) + (q << 2) + i;
          smA[r * 136 + n] = f2bf(fmaf((acc[nt2][nt][i] - mu[i]) * rs[i], g, be));
        }
      }
  }
  for (int i = t; i < 128 * 16; i += 512) {
    int row = i >> 4, c8 = (i & 15) << 3;
    *(uint4*)&smB[row * 136 + c8] = *(const uint4*)&fcw_b[row * 128 + c8];
  }
  __syncthreads();
  if (t < 256) {
    ffrag a2[8] = {{0.f,0.f,0.f,0.f},{0.f,0.f,0.f,0.f},{0.f,0.f,0.f,0.f},{0.f,0.f,0.f,0.f},
                   {0.f,0.f,0.f,0.f},{0.f,0.f,0.f,0.f},{0.f,0.f,0.f,0.f},{0.f,0.f,0.f,0.f}};
#pragma unroll
    for (int s8 = 0; s8 < 4; ++s8) {
      int k0 = s8 * 32 + q * 8;
      bfrag af = *(const bfrag*)&smA[((w << 4) + col) * 136 + k0];
#pragma unroll
      for (int nt = 0; nt < 8; ++nt) {
        bfrag bf_ = *(const bfrag*)&smB[((nt << 4) + col) * 136 + k0];
        a2[nt] = __builtin_amdgcn_mfma_f32_16x16x32_bf16(af, bf_, a2[nt], 0, 0, 0);
      }
    }
#pragma unroll
    for (int nt = 0; nt < 8; ++nt)
#pragma unroll
      for (int i = 0; i < 4; ++i) {
        int ml = (w << 4) + (q << 2) + i;
        out[(base + ml) * 128 + (nt << 4) + col] = fmaxf(a2[nt][i], 0.f);
      }
  }
}

extern "C" void kernel_launch(void* const* d_in, const int* in_sizes, int n_in,
                              void* d_out, int out_size, void* d_ws, size_t ws_size,
                              hipStream_t stream) {
  (void)in_sizes; (void)n_in; (void)out_size; (void)ws_size;
  const float* s    = (const float*)d_in[0];
  const float* w_in = (const float*)d_in[1];
  const float* cw   = (const float*)d_in[2];
  const float* cb   = (const float*)d_in[3];
  const float* xw   = (const float*)d_in[4];
  const float* dtw  = (const float*)d_in[5];
  const float* dtpb = (const float*)d_in[6];
  const float* alog = (const float*)d_in[7];
  const float* dsk  = (const float*)d_in[8];
  const float* ow   = (const float*)d_in[9];
  const float* gam  = (const float*)d_in[10];
  const float* bet  = (const float*)d_in[11];
  const float* fcw  = (const float*)d_in[12];
  float* out = (float*)d_out;
  float* ws  = (float*)d_ws;

  // float-unit offsets; all regions disjoint (audited r6; bf16 regions sized
  // as (num bf16 values)/2 floats):
  unsigned short* zsb  = (unsigned short*)(ws + 4194304);     // [4194304, 8388608)
  unsigned int*   udt  = (unsigned int*)(ws + 8388608);       // [8388608, 16777216)
  float*          Bb   = ws + 16777216;                       // [16777216, 17301504)
  float*          Cb   = ws + 17301504;                       // [17301504, 17825792)
  unsigned short* cP   = (unsigned short*)(ws + 17825792);    // [17825792, 19922944)
  unsigned short* cHe  = (unsigned short*)(ws + 19922944);    // [19922944, 22020096)
  unsigned short* w_in_b = (unsigned short*)(ws + 22020096);  // 65536 bf16 -> [22020096, 22052864)
  unsigned short* xw_b   = (unsigned short*)(ws + 22052864);  // 10240 bf16 -> [22052864, 22057984)
  unsigned short* ow_b   = (unsigned short*)(ws + 22057984);  // 32768 bf16 -> [22057984, 22074368)
  unsigned short* fcw_b  = (unsigned short*)(ws + 22074368);  // 16384 bf16 -> [22074368, 22082560)

  // 0. one-shot weight f32->bf16 (identical RNE)
  prep_weights<<<122, 256, 0, stream>>>(w_in, xw, ow, fcw, w_in_b, xw_b, ow_b, fcw_b);
  // 1. MEGA-FUSED: in_proj (W direct-from-global, 5 barriers) + conv/silu
  //    + x_proj + dt_proj + scan phase 1
  xproj_dtproj<<<512, 512, 0, stream>>>(s, w_in_b, xw_b, dtw, dtpb, cw, cb, alog,
                                        Bb, Cb, udt, zsb, cP, cHe);
  // 2. inter-chunk combine
  scan_combine<<<512, 512, 0, stream>>>(cP, cHe);
  // 3. FUSED scan phase 3 (2 parallel chunks/block) + out_proj + LN + fc + ReLU
  scan3_out_ln_fc<<<B_ * NC / 2, 512, 0, stream>>>(udt, Bb, Cb, alog, cP, dsk, zsb,
                                                   ow_b, gam, bet, fcw_b, out);
}